// Round 4
// baseline (534.188 us; speedup 1.0000x reference)
//
#include <hip/hip_runtime.h>

// ---------------------------------------------------------------------------
// SLMGAE edge scorer, round 4.
//   P = zc @ fc1_w[0:400] + b1,  Q = zc @ fc1_w[400:800]   (per node)
//   per edge: h1 = relu(P[s]+Q[d]); h2 = relu(h1@W2+b2); h3 = relu(h2@W3+b3);
//   out = h3@w4 + b4
// Round-4 changes vs round 3 (which was gather-latency bound @ 23% occupancy):
//   * counting-sort edges by source node s -> P-half gather becomes L1/L2-hit
//     (avg degree 25 => ~1-2 distinct s per 32-edge MFMA column block).
//   * weight staging via __builtin_amdgcn_global_load_lds (async, no VGPR
//     round-trip) + __launch_bounds__(256,3) -> 3 waves/SIMD target.
//   * node_gemm grid 314 -> 1570 blocks (was 1.2 blocks/CU, latency-exposed).
// ---------------------------------------------------------------------------

using u16    = unsigned short;
using bf16x8 = __attribute__((ext_vector_type(8))) short;   // 8 bf16 (4 VGPR)
using f32x4  = __attribute__((ext_vector_type(4))) float;
using f32x16 = __attribute__((ext_vector_type(16))) float;
using i32x4  = __attribute__((ext_vector_type(4))) int;

#define NN   20000   // nodes
#define NNP  20032   // nodes padded (multiple of 64)
#define KD   416     // 400 padded to multiple of 32 (col 400 = bias-one)
#define NE   500000  // edges

// fragment-order element counts
#define W1F_ELEMS (50*13*512)    // 50 n-tiles(16) x 13 kb(32) x 64 lanes x 8
#define W2F_ELEMS (7*26*512)     // 7 n-tiles(32) x 26 kb(16) x 64 x 8
#define W3F_ELEMS (4*14*512)     // 4 n-tiles(32) x 14 kb(16) x 64 x 8
#define F4_ELEMS  128
#define PREP_TOT  (W1F_ELEMS + W2F_ELEMS + W3F_ELEMS + F4_ELEMS)
#define CNT_N  20224             // histogram bins (256*79), >= NN, zero-padded

__device__ __forceinline__ u16 f2bf(float f) {              // RNE f32->bf16
  unsigned u = __float_as_uint(f);
  u += 0x7fffu + ((u >> 16) & 1u);
  return (u16)(u >> 16);
}

// async global->LDS, 16 B per lane; lds dest = wave-uniform base + lane*16
__device__ __forceinline__ void gld_lds16(const u16* g, u16* l) {
  __builtin_amdgcn_global_load_lds(
      (const __attribute__((address_space(1))) unsigned int*)g,
      (__attribute__((address_space(3))) unsigned int*)l, 16, 0, 0);
}

// ---------------------------------------------------------------------------
// K0: weight prep (fragment order, bias columns) + zero the sort histogram.
// ---------------------------------------------------------------------------
__global__ __launch_bounds__(256) void prep_w(
    const float* __restrict__ fc1, const float* __restrict__ fc1b,
    const float* __restrict__ fc2, const float* __restrict__ fc2b,
    const float* __restrict__ fc3, const float* __restrict__ fc3b,
    const float* __restrict__ fc4,
    u16* __restrict__ W1f, u16* __restrict__ W2f, u16* __restrict__ W3f,
    float* __restrict__ fc4wp, int* __restrict__ cnt)
{
  int idx = blockIdx.x * 256 + threadIdx.x;
  if (idx < W1F_ELEMS) {
    int j = idx & 7, l = (idx >> 3) & 63, t = idx >> 9;
    int kb = t % 13, g = t / 13;
    int n = g * 16 + (l & 15);
    int k = kb * 32 + (l >> 4) * 8 + j;
    float v = 0.f;
    if (k < 400) v = (n < 400) ? fc1[(size_t)k * 400 + n]
                               : fc1[(size_t)(400 + k) * 400 + (n - 400)];
    else if (k == 400 && n < 400) v = fc1b[n];
    W1f[idx] = f2bf(v);
  } else if (idx < W1F_ELEMS + W2F_ELEMS) {
    int r = idx - W1F_ELEMS;
    int j = r & 7, l = (r >> 3) & 63, t = r >> 9;
    int kb = t % 26, nt = t / 26;
    int n = nt * 32 + (l & 31);
    int k = kb * 16 + (l >> 5) * 8 + j;
    float v = 0.f;
    if (n < 200) {
      if (k < 400) v = fc2[(size_t)k * 200 + n];
      else if (k == 400) v = fc2b[n];
    }
    W2f[r] = f2bf(v);
  } else if (idx < W1F_ELEMS + W2F_ELEMS + W3F_ELEMS) {
    int r = idx - (W1F_ELEMS + W2F_ELEMS);
    int j = r & 7, l = (r >> 3) & 63, t = r >> 9;
    int kb = t % 14, nt = t / 14;
    int n = nt * 32 + (l & 31);
    int k = kb * 16 + (l >> 5) * 8 + j;
    float v = 0.f;
    if (n < 100) {
      if (k < 200) v = fc3[(size_t)k * 100 + n];
      else if (k == 200) v = fc3b[n];
    }
    W3f[r] = f2bf(v);
  } else if (idx < PREP_TOT) {
    int r = idx - (W1F_ELEMS + W2F_ELEMS + W3F_ELEMS);
    fc4wp[r] = (r < 100) ? fc4[r] : 0.f;
  } else if (idx < PREP_TOT + CNT_N) {
    cnt[idx - PREP_TOT] = 0;
  }
}

// ---------------------------------------------------------------------------
// Sort kernels: histogram by s, exclusive scan (1 block), scatter.
// Within-bucket order is nondeterministic but the per-edge result is exact,
// so output is bit-identical regardless.
// ---------------------------------------------------------------------------
__global__ __launch_bounds__(256) void edge_hist(
    const int* __restrict__ ei, int* __restrict__ cnt)
{
  int e = blockIdx.x * 256 + threadIdx.x;
  if (e < NE) atomicAdd(&cnt[ei[e]], 1);
}

__global__ __launch_bounds__(256) void edge_scan(
    const int* __restrict__ cnt, int* __restrict__ ofs)
{
  __shared__ int part[256];
  int t = threadIdx.x;
  int sum = 0;
  for (int i = 0; i < 79; i++) sum += cnt[t * 79 + i];
  part[t] = sum;
  __syncthreads();
  for (int d2 = 1; d2 < 256; d2 <<= 1) {
    int v = (t >= d2) ? part[t - d2] : 0;
    __syncthreads();
    part[t] += v;
    __syncthreads();
  }
  int run = part[t] - sum;                 // exclusive base of this chunk
  for (int i = 0; i < 79; i++) {
    ofs[t * 79 + i] = run;
    run += cnt[t * 79 + i];
  }
}

__global__ __launch_bounds__(256) void edge_scatter(
    const int* __restrict__ ei, int* __restrict__ ofs,
    int* __restrict__ ss, int* __restrict__ dd, int* __restrict__ eo)
{
  int e = blockIdx.x * 256 + threadIdx.x;
  if (e < NE) {
    int s = ei[e];
    int pos = atomicAdd(&ofs[s], 1);
    ss[pos] = s;
    dd[pos] = ei[NE + e];
    eo[pos] = e;
  }
}

// ---------------------------------------------------------------------------
// K1: per-node tiny MLP (4->64->32->16 fp32) + build zc_bf [NNP][416]
//     zc = [z(64) | m(16) | esm(320) | 1.0 at k=400 | zeros]
// ---------------------------------------------------------------------------
__global__ __launch_bounds__(256) void build_zc(
    const float* __restrict__ z, const float* __restrict__ cell,
    const float* __restrict__ esm,
    const float* __restrict__ w1, const float* __restrict__ b1,
    const float* __restrict__ w2, const float* __restrict__ b2,
    const float* __restrict__ w3, const float* __restrict__ b3,
    u16* __restrict__ zc)
{
  __shared__ float h1s[4][64];
  __shared__ float h2s[4][32];
  __shared__ float ms[4][16];
  int tid = threadIdx.x, g = tid >> 6, t = tid & 63;
  int i = blockIdx.x * 4 + g;
  bool real = (i < NN);
  float c0 = 0, c1 = 0, c2 = 0, c3 = 0;
  if (real) {
    c0 = cell[(size_t)i * 4 + 0]; c1 = cell[(size_t)i * 4 + 1];
    c2 = cell[(size_t)i * 4 + 2]; c3 = cell[(size_t)i * 4 + 3];
  }
  float h = b1[t] + c0 * w1[t] + c1 * w1[64 + t] + c2 * w1[128 + t] + c3 * w1[192 + t];
  h1s[g][t] = fmaxf(h, 0.f);
  __syncthreads();
  if (t < 32) {
    float acc = b2[t];
    #pragma unroll 8
    for (int j = 0; j < 64; j++) acc += h1s[g][j] * w2[j * 32 + t];
    h2s[g][t] = fmaxf(acc, 0.f);
  }
  __syncthreads();
  if (t < 16) {
    float acc = b3[t];
    #pragma unroll 8
    for (int j = 0; j < 32; j++) acc += h2s[g][j] * w3[j * 16 + t];
    ms[g][t] = acc;
  }
  __syncthreads();
  u16* row = zc + (size_t)i * KD;
  for (int k = t; k < KD; k += 64) {
    float v = 0.f;
    if (real) {
      if (k < 64)       v = z[(size_t)i * 64 + k];
      else if (k < 80)  v = ms[g][k - 64];
      else if (k < 400) v = esm[(size_t)i * 320 + (k - 80)];
      else if (k == 400) v = 1.0f;     // bias-one column (fc1b lives in W1f)
    }
    row[k] = f2bf(v);
  }
}

// ---------------------------------------------------------------------------
// K2: PQ[NNP][800] = zc_bf @ W1^T (bias via k=400 col), bf16 out.
// Dual 16-row A-tiles per wave; grid (157, 10): y = group of 5 col-tiles.
// ---------------------------------------------------------------------------
__global__ __launch_bounds__(256) void node_gemm(
    const u16* __restrict__ zc, const u16* __restrict__ W1f,
    u16* __restrict__ PQ)
{
  int tid = threadIdx.x, w = tid >> 6, l = tid & 63, lm = l & 15, quad = l >> 4;
  int mbase = blockIdx.x * 128 + w * 32;

  int ra = mbase + lm;       if (ra > NNP - 1) ra = NNP - 1;
  int rb = mbase + 16 + lm;  if (rb > NNP - 1) rb = NNP - 1;
  bf16x8 a0[13], a1[13];
  const u16* arow0 = zc + (size_t)ra * KD + quad * 8;
  const u16* arow1 = zc + (size_t)rb * KD + quad * 8;
  #pragma unroll
  for (int kb = 0; kb < 13; kb++) {
    a0[kb] = *(const bf16x8*)(arow0 + kb * 32);
    a1[kb] = *(const bf16x8*)(arow1 + kb * 32);
  }

  for (int nt = 0; nt < 5; nt++) {
    int g = blockIdx.y * 5 + nt;           // global 16-col tile (0..49)
    int ncol = g * 16 + lm;
    const u16* bbase = W1f + ((size_t)g * 13 * 64 + l) * 8;
    f32x4 acc0 = {0.f, 0.f, 0.f, 0.f};
    f32x4 acc1 = {0.f, 0.f, 0.f, 0.f};
    #pragma unroll
    for (int kb = 0; kb < 13; kb++) {
      bf16x8 b = *(const bf16x8*)(bbase + (size_t)kb * 512);
      acc0 = __builtin_amdgcn_mfma_f32_16x16x32_bf16(a0[kb], b, acc0, 0, 0, 0);
      acc1 = __builtin_amdgcn_mfma_f32_16x16x32_bf16(a1[kb], b, acc1, 0, 0, 0);
    }
    #pragma unroll
    for (int r = 0; r < 4; r++) {
      int row0 = mbase + quad * 4 + r;
      int row1 = row0 + 16;
      if (row0 < NNP) PQ[(size_t)row0 * 800 + ncol] = f2bf(acc0[r]);
      if (row1 < NNP) PQ[(size_t)row1 * 800 + ncol] = f2bf(acc1[r]);
    }
  }
}

// ---------------------------------------------------------------------------
// K3: edge kernel — 32 sorted edges/wave, mfma 32x32x16, async LDS staging.
// ---------------------------------------------------------------------------
__global__ __launch_bounds__(256, 3) void edge_kernel(
    const u16* __restrict__ PQ, const u16* __restrict__ W2f,
    const u16* __restrict__ W3f, const float* __restrict__ fc4wp,
    const float* __restrict__ fc4b,
    const int* __restrict__ ss, const int* __restrict__ dd,
    const int* __restrict__ eo, float* __restrict__ out)
{
  __shared__ __align__(16) u16 wsm[26 * 512];   // 26.6 KB weight-tile stage

  int tid = threadIdx.x, w = tid >> 6, l = tid & 63;
  int c = l & 31, h = l >> 5;
  int i = blockIdx.x * 128 + w * 32 + c;
  int ic = i < NE ? i : NE - 1;
  int s = ss[ic], d = dd[ic], oe = eo[ic];
  const u16* prow = PQ + (size_t)s * 800 + h * 8;        // P (pre-biased)
  const u16* qrow = PQ + (size_t)d * 800 + 400 + h * 8;  // Q

  // ---- gather -> h1 B-frags (kb 0..24 real; kb 25 = bias-one) -------------
  i32x4 h1i[25];
  #pragma unroll
  for (int kb = 0; kb < 25; kb++) {
    i32x4 pv = *(const i32x4*)(prow + kb * 16);
    i32x4 qv = *(const i32x4*)(qrow + kb * 16);
    i32x4 r;
    #pragma unroll
    for (int j2 = 0; j2 < 4; j2++) {
      unsigned pu = (unsigned)pv[j2], qu = (unsigned)qv[j2];
      float lo = __uint_as_float(pu << 16) + __uint_as_float(qu << 16);
      float hi = __uint_as_float(pu & 0xFFFF0000u) + __uint_as_float(qu & 0xFFFF0000u);
      lo = fmaxf(lo, 0.f);
      hi = fmaxf(hi, 0.f);
      unsigned ul = __float_as_uint(lo); ul += 0x7fffu + ((ul >> 16) & 1u);
      unsigned uh = __float_as_uint(hi); uh += 0x7fffu + ((uh >> 16) & 1u);
      r[j2] = (int)((ul >> 16) | (uh & 0xFFFF0000u));
    }
    h1i[kb] = r;
  }
  i32x4 bias1 = {0, 0, 0, 0};
  if (h == 0) bias1[0] = 0x3f80;   // h1[k=400] = 1.0 (bf16) for every edge

  // ---- fc2: 7 ntiles of 32 neurons; weights via async LDS stage -----------
  int p2[7][8];
  for (int nt = 0; nt < 7; nt++) {
    if (nt) __syncthreads();                    // prev tile's reads complete
    for (int kb = w; kb < 26; kb += 4)          // async stage 26 KB
      gld_lds16(W2f + (((size_t)nt * 26 + kb) * 64 + l) * 8, &wsm[kb * 512 + l * 8]);
    __syncthreads();                            // drains vmcnt + barrier
    f32x16 acc = {0.f,0.f,0.f,0.f,0.f,0.f,0.f,0.f,0.f,0.f,0.f,0.f,0.f,0.f,0.f,0.f};
    #pragma unroll
    for (int kb = 0; kb < 25; kb++) {
      bf16x8 a = *(const bf16x8*)&wsm[kb * 512 + l * 8];
      acc = __builtin_amdgcn_mfma_f32_32x32x16_bf16(
          a, __builtin_bit_cast(bf16x8, h1i[kb]), acc, 0, 0, 0);
    }
    {  // kb = 25: bias column k=400
      bf16x8 a = *(const bf16x8*)&wsm[25 * 512 + l * 8];
      acc = __builtin_amdgcn_mfma_f32_32x32x16_bf16(
          a, __builtin_bit_cast(bf16x8, bias1), acc, 0, 0, 0);
    }
    #pragma unroll
    for (int q = 0; q < 8; q++) {   // relu + RNE-pack regs (2q, 2q+1)
      float v0 = fmaxf(acc[2 * q], 0.f);
      float v1 = fmaxf(acc[2 * q + 1], 0.f);
      unsigned u0 = __float_as_uint(v0); u0 += 0x7fffu + ((u0 >> 16) & 1u);
      unsigned u1 = __float_as_uint(v1); u1 += 0x7fffu + ((u1 >> 16) & 1u);
      p2[nt][q] = (int)((u0 >> 16) | (u1 & 0xFFFF0000u));
    }
  }

  // ---- transpose: C-layout h2 -> fc3 B-frags via shfl_xor(32) -------------
  i32x4 b2f[14];
  #pragma unroll
  for (int kb3 = 0; kb3 < 14; kb3++) {
    int nt = kb3 >> 1;
    i32x4 f;
    #pragma unroll
    for (int jj = 0; jj < 4; jj++) {
      int q0 = (jj & 1) + 4 * (kb3 & 1);
      if (jj < 2) {        // source lives in lower half (h_s = 0)
        int x = __shfl_xor(p2[nt][q0 + 2], 32);
        f[jj] = h ? x : p2[nt][q0];
      } else {             // source lives in upper half (h_s = 1)
        int y = __shfl_xor(p2[nt][q0], 32);
        f[jj] = h ? p2[nt][q0 + 2] : y;
      }
    }
    if (kb3 == 12 && h) f[0] |= 0x3f80;   // h2[k2=200] = 1.0 (fc3 bias-one)
    b2f[kb3] = f;
  }

  // ---- fc3 + fc4 ----------------------------------------------------------
  float osum = 0.f;
  for (int nt3 = 0; nt3 < 4; nt3++) {
    __syncthreads();                            // prev tile's reads complete
    for (int kb = w; kb < 14; kb += 4)          // async stage 14 KB
      gld_lds16(W3f + (((size_t)nt3 * 14 + kb) * 64 + l) * 8, &wsm[kb * 512 + l * 8]);
    __syncthreads();
    f32x16 acc = {0.f,0.f,0.f,0.f,0.f,0.f,0.f,0.f,0.f,0.f,0.f,0.f,0.f,0.f,0.f,0.f};
    #pragma unroll
    for (int kb3 = 0; kb3 < 14; kb3++) {
      bf16x8 a = *(const bf16x8*)&wsm[kb3 * 512 + l * 8];
      acc = __builtin_amdgcn_mfma_f32_32x32x16_bf16(
          a, __builtin_bit_cast(bf16x8, b2f[kb3]), acc, 0, 0, 0);
    }
    #pragma unroll
    for (int r = 0; r < 16; r++) {
      int rho = (r & 3) + 8 * (r >> 2) + 4 * h + 32 * nt3;
      osum += fmaxf(acc[r], 0.f) * fc4wp[rho];   // pad rows: 0 * 0
    }
  }
  osum += __shfl_xor(osum, 32);     // combine the two k-halves of this edge
  if (h == 0 && i < NE) out[oe] = osum + fc4b[0];
}

// ---------------------------------------------------------------------------
extern "C" void kernel_launch(void* const* d_in, const int* in_sizes, int n_in,
                              void* d_out, int out_size, void* d_ws, size_t ws_size,
                              hipStream_t stream) {
  (void)in_sizes; (void)n_in; (void)out_size; (void)ws_size;
  const float* z    = (const float*)d_in[0];
  const int*   ei   = (const int*)d_in[1];
  const float* cell = (const float*)d_in[2];
  const float* esm  = (const float*)d_in[3];
  const float* w1   = (const float*)d_in[4];
  const float* b1   = (const float*)d_in[5];
  const float* w2   = (const float*)d_in[6];
  const float* b2   = (const float*)d_in[7];
  const float* w3   = (const float*)d_in[8];
  const float* b3   = (const float*)d_in[9];
  const float* fc1w = (const float*)d_in[10];
  const float* fc1b = (const float*)d_in[11];
  const float* fc2w = (const float*)d_in[12];
  const float* fc2b = (const float*)d_in[13];
  const float* fc3w = (const float*)d_in[14];
  const float* fc3b = (const float*)d_in[15];
  const float* fc4w = (const float*)d_in[16];
  const float* fc4b = (const float*)d_in[17];
  float* out = (float*)d_out;

  // workspace layout (u16 units then ints, all 16B-aligned): ~56 MB
  u16* zc  = (u16*)d_ws;                        // NNP*416
  u16* PQ  = zc  + (size_t)NNP * KD;            // NNP*800
  u16* W1f = PQ  + (size_t)NNP * 800;           // 332800
  u16* W2f = W1f + W1F_ELEMS;                   // 93184
  u16* W3f = W2f + W2F_ELEMS;                   // 28672
  float* fc4wp = (float*)(W3f + W3F_ELEMS);     // 128 f32
  int* cnt = (int*)(fc4wp + F4_ELEMS);          // 20224
  int* ofs = cnt + CNT_N;                       // 20224
  int* ss  = ofs + CNT_N;                       // 500000
  int* dd  = ss + NE;                           // 500000
  int* eo  = dd + NE;                           // 500000

  prep_w<<<(PREP_TOT + CNT_N + 255) / 256, 256, 0, stream>>>(
      fc1w, fc1b, fc2w, fc2b, fc3w, fc3b, fc4w, W1f, W2f, W3f, fc4wp, cnt);
  edge_hist<<<(NE + 255) / 256, 256, 0, stream>>>(ei, cnt);
  edge_scan<<<1, 256, 0, stream>>>(cnt, ofs);
  edge_scatter<<<(NE + 255) / 256, 256, 0, stream>>>(ei, ofs, ss, dd, eo);
  build_zc<<<NNP / 4, 256, 0, stream>>>(z, cell, esm, w1, b1, w2, b2, w3, b3, zc);
  node_gemm<<<dim3((NNP + 127) / 128, 10), 256, 0, stream>>>(zc, W1f, PQ);
  edge_kernel<<<(NE + 127) / 128, 256, 0, stream>>>(
      PQ, W2f, W3f, fc4wp, fc4b, ss, dd, eo, out);
}